// Round 2
// baseline (524.058 us; speedup 1.0000x reference)
//
#include <hip/hip_runtime.h>
#include <hip/hip_bf16.h>
#include <math.h>

// Problem constants
#define NB    2
#define NSEQ  512
#define DIN   1024
#define DCOND 128
#define NF    8
#define NH    16
#define HD    64
constexpr float LN_EPS = 1e-5f;

// d_ws layout (bytes):
//   cond : 8*1024 f32                     32 KB   @ 0
//   Ahi  : (16,512,1024) bf16          16.78 MB   @ 32768
//   Alo  : same                                  @ 16809984
//   Bhi  : (2048,1024) bf16             4.19 MB   @ 33587200
//   Blo  : same                                  @ 37781504
//   Qb   : (256,512,64) f32            33.55 MB   @ 41975808
//   Kb   : same                                  @ 75530240
// total ~109.1 MB
#define WS_COND 0
#define WS_AHI  32768
#define WS_ALO  16809984
#define WS_BHI  33587200
#define WS_BLO  37781504
#define WS_QB   41975808
#define WS_KB   75530240

using bf16x8 = __attribute__((ext_vector_type(8))) short;
using f32x4  = __attribute__((ext_vector_type(4))) float;

__device__ __forceinline__ unsigned short f2bf(float x) {
    unsigned int u = __float_as_uint(x);
    unsigned int r = (u + 0x7fffu + ((u >> 16) & 1u)) >> 16;   // RNE
    return (unsigned short)r;
}
__device__ __forceinline__ float bf2f(unsigned short h) {
    return __uint_as_float(((unsigned int)h) << 16);
}

__device__ __forceinline__ void gload16(const void* g, void* l) {
    __builtin_amdgcn_global_load_lds(
        (__attribute__((address_space(1))) void*)(const_cast<void*>(g)),
        (__attribute__((address_space(3))) void*)l, 16, 0, 0);
}

// ---------------------------------------------------------------------------
// Kernel A: cond[f,:] = LayerNorm((w_c @ code)[:,f]) * gamma + beta
// ---------------------------------------------------------------------------
__global__ __launch_bounds__(256)
void cond_kernel(const float* __restrict__ w_c, const float* __restrict__ code,
                 const float* __restrict__ gamma, const float* __restrict__ beta,
                 float* __restrict__ cond)
{
    __shared__ float sc[DCOND];
    __shared__ float rs[256], rs2[256];
    const int f = blockIdx.x;
    const int t = threadIdx.x;

    if (t < DCOND) sc[t] = code[t * NF + f];
    __syncthreads();

    float hv[4];
    float s = 0.f, s2 = 0.f;
#pragma unroll
    for (int r = 0; r < 4; ++r) {
        const int d = r * 256 + t;
        const float* row = w_c + (size_t)d * DCOND;
        float acc = 0.f;
#pragma unroll 8
        for (int c = 0; c < DCOND; c += 4) {
            float4 wv = *(const float4*)(row + c);
            float4 cv = *(const float4*)(sc + c);
            acc += wv.x * cv.x + wv.y * cv.y + wv.z * cv.z + wv.w * cv.w;
        }
        hv[r] = acc; s += acc; s2 += acc * acc;
    }
    rs[t] = s; rs2[t] = s2;
    __syncthreads();
    for (int off = 128; off > 0; off >>= 1) {
        if (t < off) { rs[t] += rs[t + off]; rs2[t] += rs2[t + off]; }
        __syncthreads();
    }
    const float mu  = rs[0] * (1.f / DIN);
    const float var = rs2[0] * (1.f / DIN) - mu * mu;
    const float rstd = rsqrtf(var + LN_EPS);
#pragma unroll
    for (int r = 0; r < 4; ++r) {
        const int d = r * 256 + t;
        cond[f * DIN + d] = (hv[r] - mu) * rstd * gamma[d] + beta[d];
    }
}

// ---------------------------------------------------------------------------
// Kernel B1: split modx = x * cond  ->  Ahi/Alo bf16, layout [bf][n][d]
// 1,048,576 threads, 8 elems each
// ---------------------------------------------------------------------------
__global__ __launch_bounds__(256)
void split_x_kernel(const float* __restrict__ x, const float* __restrict__ cond,
                    short* __restrict__ Ahi, short* __restrict__ Alo)
{
    const unsigned idx = blockIdx.x * 256 + threadIdx.x;   // < 1048576
    const int d  = (idx & 127) * 8;
    const int n  = (idx >> 7) & 511;
    const int bf = idx >> 16;
    const int b  = bf >> 3, f = bf & 7;

    const float* xs = x + ((size_t)b * NSEQ + n) * DIN + d;
    const float* cs = cond + f * DIN + d;
    float4 x0 = *(const float4*)xs,      x1 = *(const float4*)(xs + 4);
    float4 c0 = *(const float4*)cs,      c1 = *(const float4*)(cs + 4);

    float m[8] = { x0.x*c0.x, x0.y*c0.y, x0.z*c0.z, x0.w*c0.w,
                   x1.x*c1.x, x1.y*c1.y, x1.z*c1.z, x1.w*c1.w };
    bf16x8 hi, lo;
#pragma unroll
    for (int i = 0; i < 8; ++i) {
        unsigned short h = f2bf(m[i]);
        hi[i] = (short)h;
        lo[i] = (short)f2bf(m[i] - bf2f(h));
    }
    *(bf16x8*)(Ahi + (size_t)idx * 8) = hi;
    *(bf16x8*)(Alo + (size_t)idx * 8) = lo;
}

// ---------------------------------------------------------------------------
// Kernel B2: split W rows 0..2047 -> Bhi/Blo bf16 (same layout as W)
// 262,144 threads, 8 elems each
// ---------------------------------------------------------------------------
__global__ __launch_bounds__(256)
void split_w_kernel(const float* __restrict__ W,
                    short* __restrict__ Bhi, short* __restrict__ Blo)
{
    const unsigned idx = blockIdx.x * 256 + threadIdx.x;   // < 262144
    const float* ws = W + (size_t)idx * 8;
    float4 w0 = *(const float4*)ws, w1 = *(const float4*)(ws + 4);
    float m[8] = { w0.x, w0.y, w0.z, w0.w, w1.x, w1.y, w1.z, w1.w };
    bf16x8 hi, lo;
#pragma unroll
    for (int i = 0; i < 8; ++i) {
        unsigned short h = f2bf(m[i]);
        hi[i] = (short)h;
        lo[i] = (short)f2bf(m[i] - bf2f(h));
    }
    *(bf16x8*)(Bhi + (size_t)idx * 8) = hi;
    *(bf16x8*)(Blo + (size_t)idx * 8) = lo;
}

// ---------------------------------------------------------------------------
// Kernel C: bf16x3 MFMA projection.
//   C[n][e] = sum_k modx[n][k] * W[e][k]   (per bf slab), + bias, scatter q/k
// Block: 256 thr (4 waves 2x2), tile 128x128, BK=32.
// LDS tiles [128][32] bf16, XOR swizzle: 16B-slot ^= (row>>1)&3.
// Staged via global_load_lds w/ pre-swizzled per-lane global addresses.
// grid = (16 col-tiles, 4 row-tiles, 16 bf)
// ---------------------------------------------------------------------------
__global__ __launch_bounds__(256, 2)
void proj_mfma_kernel(const short* __restrict__ Ahi_g, const short* __restrict__ Alo_g,
                      const short* __restrict__ Bhi_g, const short* __restrict__ Blo_g,
                      const float* __restrict__ bias,
                      float* __restrict__ Qb, float* __restrict__ Kb)
{
    __shared__ short sAhi[128 * 32];
    __shared__ short sAlo[128 * 32];
    __shared__ short sBhi[128 * 32];
    __shared__ short sBlo[128 * 32];

    const int bf   = blockIdx.z;
    const int n0   = blockIdx.y * 128;
    const int bcol = blockIdx.x * 128;
    const int t    = threadIdx.x;
    const int w    = t >> 6, lane = t & 63;
    const int wr   = w >> 1, wc = w & 1;

    // staging addresses: wave w stages rows 32w..32w+31 of each array
    const int rl = lane >> 2;                       // row within 16-row chunk
    const int sl = (lane & 3) ^ ((lane >> 3) & 3);  // swizzled 16B k-slot
    const size_t aoff = ((size_t)bf * NSEQ + n0 + 32 * w + rl) * DIN + sl * 8;
    const size_t boff = ((size_t)(bcol + 32 * w + rl)) * DIN + sl * 8;
    const short* gAh = Ahi_g + aoff;
    const short* gAl = Alo_g + aoff;
    const short* gBh = Bhi_g + boff;
    const short* gBl = Blo_g + boff;
    short* dAh = sAhi + 1024 * w;   // chunk 2w base (shorts); +512 = chunk 2w+1
    short* dAl = sAlo + 1024 * w;
    short* dBh = sBhi + 1024 * w;
    short* dBl = sBlo + 1024 * w;

    // fragment LDS offsets (shorts), loop-invariant
    int offA[4], offB[4];
    const int g = lane >> 4;
#pragma unroll
    for (int fi = 0; fi < 4; ++fi) {
        int r  = wr * 64 + fi * 16 + (lane & 15);
        offA[fi] = r * 32 + ((g ^ ((r >> 1) & 3)) * 8);
        int rb = wc * 64 + fi * 16 + (lane & 15);
        offB[fi] = rb * 32 + ((g ^ ((rb >> 1) & 3)) * 8);
    }

    f32x4 acc[4][4];
#pragma unroll
    for (int i = 0; i < 4; ++i)
#pragma unroll
        for (int j = 0; j < 4; ++j) acc[i][j] = (f32x4){0.f, 0.f, 0.f, 0.f};

    for (int kb = 0; kb < DIN; kb += 32) {
        __syncthreads();                         // prev tile fully consumed
        gload16(gAh + kb, dAh);  gload16(gAh + kb + 16 * DIN, dAh + 512);
        gload16(gAl + kb, dAl);  gload16(gAl + kb + 16 * DIN, dAl + 512);
        gload16(gBh + kb, dBh);  gload16(gBh + kb + 16 * DIN, dBh + 512);
        gload16(gBl + kb, dBl);  gload16(gBl + kb + 16 * DIN, dBl + 512);
        __syncthreads();                         // drains vmcnt: tile ready

        bf16x8 Ah[4], Al[4], Bh[4], Bl[4];
#pragma unroll
        for (int fi = 0; fi < 4; ++fi) {
            Ah[fi] = *(const bf16x8*)(sAhi + offA[fi]);
            Al[fi] = *(const bf16x8*)(sAlo + offA[fi]);
            Bh[fi] = *(const bf16x8*)(sBhi + offB[fi]);
            Bl[fi] = *(const bf16x8*)(sBlo + offB[fi]);
        }
#pragma unroll
        for (int i = 0; i < 4; ++i)
#pragma unroll
            for (int j = 0; j < 4; ++j) {
                acc[i][j] = __builtin_amdgcn_mfma_f32_16x16x32_bf16(Ah[i], Bh[j], acc[i][j], 0, 0, 0);
                acc[i][j] = __builtin_amdgcn_mfma_f32_16x16x32_bf16(Ah[i], Bl[j], acc[i][j], 0, 0, 0);
                acc[i][j] = __builtin_amdgcn_mfma_f32_16x16x32_bf16(Al[i], Bh[j], acc[i][j], 0, 0, 0);
            }
    }

    // epilogue: +bias, scatter to Qb/Kb [bf*16+h][n][dd] f32.
    // e-range of a block is 128-wide & 128-aligned -> q/k uniform per block.
#pragma unroll
    for (int j = 0; j < 4; ++j) {
        const int e = bcol + wc * 64 + j * 16 + (lane & 15);
        const float bv = bias[e];
        const int ek = e & 1023;
        float* dst = ((e < DIN) ? Qb : Kb)
                   + ((size_t)(bf * NH + (ek >> 6)) * NSEQ) * HD + (ek & 63);
#pragma unroll
        for (int i = 0; i < 4; ++i) {
            const int rbase = n0 + wr * 64 + i * 16 + (lane >> 4) * 4;
            f32x4 v = acc[i][j];
#pragma unroll
            for (int rg = 0; rg < 4; ++rg)
                dst[(size_t)(rbase + rg) * HD] = v[rg] + bv;
        }
    }
}

// ---------------------------------------------------------------------------
// Kernel D: scores + fused softmax.  Block: 64 q-rows x 512 cols of one (b,h,f).
// f32 VALU outer product; acc[8][4][4] holds the full 512-col strip.
// Softmax row-reduce via __shfl_xor over 16-lane groups; writes final attn.
// grid = (8 row-tiles, 256 bfh)
// ---------------------------------------------------------------------------
__global__ __launch_bounds__(256, 2)
void scores_smx_kernel(const float* __restrict__ Qb, const float* __restrict__ Kb,
                       float* __restrict__ out)
{
    constexpr int LQ = 68;
    __shared__ float Qs[HD][LQ];   // [d][row]
    __shared__ float Ks[HD][LQ];   // [d][col]

    const int bfh = blockIdx.y;            // (b*8+f)*16+h
    const int rt  = blockIdx.x;
    const int t = threadIdx.x, tx = t & 15, ty = t >> 4;

    const float* Qp = Qb + ((size_t)bfh * NSEQ + rt * 64) * HD;
    const float* Kp = Kb + (size_t)bfh * NSEQ * HD;

    const int b = bfh >> 7, f = (bfh >> 4) & 7, h = bfh & 15;
    const size_t obase = ((((size_t)(b * NH + h)) * NF + f) * NSEQ + rt * 64) * NSEQ;

    const int li = t >> 2, lg0 = t & 3;

    // stage Q tile (d-major)
#pragma unroll
    for (int gg = 0; gg < 4; ++gg) {
        const int gq = lg0 + gg * 4;
        float4 v = *(const float4*)(Qp + (size_t)li * HD + gq * 4);
        Qs[gq * 4 + 0][li] = v.x; Qs[gq * 4 + 1][li] = v.y;
        Qs[gq * 4 + 2][li] = v.z; Qs[gq * 4 + 3][li] = v.w;
    }

    float acc[8][4][4];
#pragma unroll
    for (int ct = 0; ct < 8; ++ct)
#pragma unroll
        for (int i = 0; i < 4; ++i)
#pragma unroll
            for (int j = 0; j < 4; ++j) acc[ct][i][j] = 0.f;

#pragma unroll
    for (int ct = 0; ct < 8; ++ct) {
        __syncthreads();   // prev Ks consumed (1st iter: Qs visible)
#pragma unroll
        for (int gg = 0; gg < 4; ++gg) {
            const int gq = lg0 + gg * 4;
            float4 v = *(const float4*)(Kp + (size_t)(ct * 64 + li) * HD + gq * 4);
            Ks[gq * 4 + 0][li] = v.x; Ks[gq * 4 + 1][li] = v.y;
            Ks[gq * 4 + 2][li] = v.z; Ks[gq * 4 + 3][li] = v.w;
        }
        __syncthreads();
#pragma unroll 4
        for (int d = 0; d < HD; ++d) {
            float4 a = *(const float4*)&Qs[d][ty * 4];
            float4 bb = *(const float4*)&Ks[d][tx * 4];
            float av[4] = {a.x, a.y, a.z, a.w};
            float bv[4] = {bb.x, bb.y, bb.z, bb.w};
#pragma unroll
            for (int i = 0; i < 4; ++i)
#pragma unroll
                for (int j = 0; j < 4; ++j)
                    acc[ct][i][j] += av[i] * bv[j];
        }
    }

    // fused softmax over each row (16 lanes with same ty hold the row)
#pragma unroll
    for (int i = 0; i < 4; ++i) {
        float m = -1e30f;
#pragma unroll
        for (int ct = 0; ct < 8; ++ct)
#pragma unroll
            for (int j = 0; j < 4; ++j) m = fmaxf(m, acc[ct][i][j]);
        m = fmaxf(m, __shfl_xor(m, 1));
        m = fmaxf(m, __shfl_xor(m, 2));
        m = fmaxf(m, __shfl_xor(m, 4));
        m = fmaxf(m, __shfl_xor(m, 8));

        float s = 0.f;
#pragma unroll
        for (int ct = 0; ct < 8; ++ct)
#pragma unroll
            for (int j = 0; j < 4; ++j) {
                float e = __expf((acc[ct][i][j] - m) * 0.125f);
                acc[ct][i][j] = e;
                s += e;
            }
        s += __shfl_xor(s, 1);
        s += __shfl_xor(s, 2);
        s += __shfl_xor(s, 4);
        s += __shfl_xor(s, 8);
        const float inv = 1.f / s;

        const size_t rowoff = obase + (size_t)(ty * 4 + i) * NSEQ;
#pragma unroll
        for (int ct = 0; ct < 8; ++ct) {
            float4 v = make_float4(acc[ct][i][0] * inv, acc[ct][i][1] * inv,
                                   acc[ct][i][2] * inv, acc[ct][i][3] * inv);
            *(float4*)(out + rowoff + ct * 64 + tx * 4) = v;
        }
    }
}

// ---------------------------------------------------------------------------
extern "C" void kernel_launch(void* const* d_in, const int* in_sizes, int n_in,
                              void* d_out, int out_size, void* d_ws, size_t ws_size,
                              hipStream_t stream)
{
    const float* x     = (const float*)d_in[0];
    const float* code  = (const float*)d_in[1];
    const float* w_c   = (const float*)d_in[2];
    const float* W     = (const float*)d_in[3];
    const float* bias  = (const float*)d_in[4];
    const float* gamma = (const float*)d_in[5];
    const float* beta  = (const float*)d_in[6];
    float* out = (float*)d_out;

    char* ws = (char*)d_ws;
    float* cond = (float*)(ws + WS_COND);
    short* Ahi  = (short*)(ws + WS_AHI);
    short* Alo  = (short*)(ws + WS_ALO);
    short* Bhi  = (short*)(ws + WS_BHI);
    short* Blo  = (short*)(ws + WS_BLO);
    float* Qb   = (float*)(ws + WS_QB);
    float* Kb   = (float*)(ws + WS_KB);

    cond_kernel<<<NF, 256, 0, stream>>>(w_c, code, gamma, beta, cond);
    split_x_kernel<<<4096, 256, 0, stream>>>(x, cond, Ahi, Alo);
    split_w_kernel<<<1024, 256, 0, stream>>>(W, Bhi, Blo);

    dim3 gP(16, 4, NB * NF);
    proj_mfma_kernel<<<gP, 256, 0, stream>>>(Ahi, Alo, Bhi, Blo, bias, Qb, Kb);

    dim3 gS(8, NB * NF * NH);
    scores_smx_kernel<<<gS, 256, 0, stream>>>(Qb, Kb, out);
}

// Round 7
// 469.710 us; speedup vs baseline: 1.1157x; 1.1157x over previous
//
#include <hip/hip_runtime.h>
#include <hip/hip_bf16.h>
#include <math.h>

// Problem constants
#define NB    2
#define NSEQ  512
#define DIN   1024
#define DCOND 128
#define NF    8
#define NH    16
#define HD    64
constexpr float LN_EPS = 1e-5f;

// d_ws layout (bytes):
//   cond : 8*1024 f32                     32 KB   @ 0
//   Ahi  : (16,512,1024) bf16          16.78 MB   @ 32768
//   Alo  : same                                  @ 16809984
//   Bhi  : (2048,1024) bf16             4.19 MB   @ 33587200
//   Blo  : same                                  @ 37781504
//   Qb   : (256,512,64) f32            33.55 MB   @ 41975808
//   Kb   : same                                  @ 75530240
#define WS_COND 0
#define WS_AHI  32768
#define WS_ALO  16809984
#define WS_BHI  33587200
#define WS_BLO  37781504
#define WS_QB   41975808
#define WS_KB   75530240

using bf16x8 = __attribute__((ext_vector_type(8))) short;
using f32x4  = __attribute__((ext_vector_type(4))) float;

__device__ __forceinline__ unsigned short f2bf(float x) {
    unsigned int u = __float_as_uint(x);
    unsigned int r = (u + 0x7fffu + ((u >> 16) & 1u)) >> 16;   // RNE
    return (unsigned short)r;
}
__device__ __forceinline__ float bf2f(unsigned short h) {
    return __uint_as_float(((unsigned int)h) << 16);
}

__device__ __forceinline__ void gload16(const void* g, void* l) {
    __builtin_amdgcn_global_load_lds(
        (__attribute__((address_space(1))) void*)(const_cast<void*>(g)),
        (__attribute__((address_space(3))) void*)l, 16, 0, 0);
}

// in-register f32 -> bf16 hi/lo split (RTZ hi; cross terms catch residual)
struct BF2 { bf16x8 hi, lo; };
__device__ __forceinline__ BF2 split8(float4 a, float4 b) {
    float v[8] = {a.x, a.y, a.z, a.w, b.x, b.y, b.z, b.w};
    BF2 r;
#pragma unroll
    for (int i = 0; i < 8; ++i) {
        unsigned u  = __float_as_uint(v[i]);
        unsigned uh = u & 0xffff0000u;
        r.hi[i] = (short)(u >> 16);
        float l = v[i] - __uint_as_float(uh);
        r.lo[i] = (short)(__float_as_uint(l) >> 16);
    }
    return r;
}

// ---------------------------------------------------------------------------
// Kernel A: cond[f,:] = LayerNorm((w_c @ code)[:,f]) * gamma + beta
// ---------------------------------------------------------------------------
__global__ __launch_bounds__(256)
void cond_kernel(const float* __restrict__ w_c, const float* __restrict__ code,
                 const float* __restrict__ gamma, const float* __restrict__ beta,
                 float* __restrict__ cond)
{
    __shared__ float sc[DCOND];
    __shared__ float rs[256], rs2[256];
    const int f = blockIdx.x;
    const int t = threadIdx.x;

    if (t < DCOND) sc[t] = code[t * NF + f];
    __syncthreads();

    float hv[4];
    float s = 0.f, s2 = 0.f;
#pragma unroll
    for (int r = 0; r < 4; ++r) {
        const int d = r * 256 + t;
        const float* row = w_c + (size_t)d * DCOND;
        float acc = 0.f;
#pragma unroll 8
        for (int c = 0; c < DCOND; c += 4) {
            float4 wv = *(const float4*)(row + c);
            float4 cv = *(const float4*)(sc + c);
            acc += wv.x * cv.x + wv.y * cv.y + wv.z * cv.z + wv.w * cv.w;
        }
        hv[r] = acc; s += acc; s2 += acc * acc;
    }
    rs[t] = s; rs2[t] = s2;
    __syncthreads();
    for (int off = 128; off > 0; off >>= 1) {
        if (t < off) { rs[t] += rs[t + off]; rs2[t] += rs2[t + off]; }
        __syncthreads();
    }
    const float mu  = rs[0] * (1.f / DIN);
    const float var = rs2[0] * (1.f / DIN) - mu * mu;
    const float rstd = rsqrtf(var + LN_EPS);
#pragma unroll
    for (int r = 0; r < 4; ++r) {
        const int d = r * 256 + t;
        cond[f * DIN + d] = (hv[r] - mu) * rstd * gamma[d] + beta[d];
    }
}

// ---------------------------------------------------------------------------
// Kernel B1: split modx = x * cond  ->  Ahi/Alo bf16, layout [bf][n][d]
// ---------------------------------------------------------------------------
__global__ __launch_bounds__(256)
void split_x_kernel(const float* __restrict__ x, const float* __restrict__ cond,
                    short* __restrict__ Ahi, short* __restrict__ Alo)
{
    const unsigned idx = blockIdx.x * 256 + threadIdx.x;   // < 1048576
    const int d  = (idx & 127) * 8;
    const int n  = (idx >> 7) & 511;
    const int bf = idx >> 16;
    const int b  = bf >> 3, f = bf & 7;

    const float* xs = x + ((size_t)b * NSEQ + n) * DIN + d;
    const float* cs = cond + f * DIN + d;
    float4 x0 = *(const float4*)xs, x1 = *(const float4*)(xs + 4);
    float4 c0 = *(const float4*)cs, c1 = *(const float4*)(cs + 4);

    float m[8] = { x0.x*c0.x, x0.y*c0.y, x0.z*c0.z, x0.w*c0.w,
                   x1.x*c1.x, x1.y*c1.y, x1.z*c1.z, x1.w*c1.w };
    bf16x8 hi, lo;
#pragma unroll
    for (int i = 0; i < 8; ++i) {
        unsigned short h = f2bf(m[i]);
        hi[i] = (short)h;
        lo[i] = (short)f2bf(m[i] - bf2f(h));
    }
    *(bf16x8*)(Ahi + (size_t)idx * 8) = hi;
    *(bf16x8*)(Alo + (size_t)idx * 8) = lo;
}

// ---------------------------------------------------------------------------
// Kernel B2: split W rows 0..2047 -> Bhi/Blo bf16
// ---------------------------------------------------------------------------
__global__ __launch_bounds__(256)
void split_w_kernel(const float* __restrict__ W,
                    short* __restrict__ Bhi, short* __restrict__ Blo)
{
    const unsigned idx = blockIdx.x * 256 + threadIdx.x;   // < 262144
    const float* ws = W + (size_t)idx * 8;
    float4 w0 = *(const float4*)ws, w1 = *(const float4*)(ws + 4);
    float m[8] = { w0.x, w0.y, w0.z, w0.w, w1.x, w1.y, w1.z, w1.w };
    bf16x8 hi, lo;
#pragma unroll
    for (int i = 0; i < 8; ++i) {
        unsigned short h = f2bf(m[i]);
        hi[i] = (short)h;
        lo[i] = (short)f2bf(m[i] - bf2f(h));
    }
    *(bf16x8*)(Bhi + (size_t)idx * 8) = hi;
    *(bf16x8*)(Blo + (size_t)idx * 8) = lo;
}

// ---------------------------------------------------------------------------
// Kernel C: bf16x3 MFMA projection (round-2-validated structure)
// ---------------------------------------------------------------------------
__global__ __launch_bounds__(256, 2)
void proj_mfma_kernel(const short* __restrict__ Ahi_g, const short* __restrict__ Alo_g,
                      const short* __restrict__ Bhi_g, const short* __restrict__ Blo_g,
                      const float* __restrict__ bias,
                      float* __restrict__ Qb, float* __restrict__ Kb)
{
    __shared__ short sAhi[128 * 32];
    __shared__ short sAlo[128 * 32];
    __shared__ short sBhi[128 * 32];
    __shared__ short sBlo[128 * 32];

    const int bf   = blockIdx.z;
    const int n0   = blockIdx.y * 128;
    const int bcol = blockIdx.x * 128;
    const int t    = threadIdx.x;
    const int w    = t >> 6, lane = t & 63;
    const int wr   = w >> 1, wc = w & 1;

    const int rl = lane >> 2;
    const int sl = (lane & 3) ^ ((lane >> 3) & 3);
    const size_t aoff = ((size_t)bf * NSEQ + n0 + 32 * w + rl) * DIN + sl * 8;
    const size_t boff = ((size_t)(bcol + 32 * w + rl)) * DIN + sl * 8;
    const short* gAh = Ahi_g + aoff;
    const short* gAl = Alo_g + aoff;
    const short* gBh = Bhi_g + boff;
    const short* gBl = Blo_g + boff;
    short* dAh = sAhi + 1024 * w;
    short* dAl = sAlo + 1024 * w;
    short* dBh = sBhi + 1024 * w;
    short* dBl = sBlo + 1024 * w;

    int offA[4], offB[4];
    const int g = lane >> 4;
#pragma unroll
    for (int fi = 0; fi < 4; ++fi) {
        int r  = wr * 64 + fi * 16 + (lane & 15);
        offA[fi] = r * 32 + ((g ^ ((r >> 1) & 3)) * 8);
        int rb = wc * 64 + fi * 16 + (lane & 15);
        offB[fi] = rb * 32 + ((g ^ ((rb >> 1) & 3)) * 8);
    }

    f32x4 acc[4][4];
#pragma unroll
    for (int i = 0; i < 4; ++i)
#pragma unroll
        for (int j = 0; j < 4; ++j) acc[i][j] = (f32x4){0.f, 0.f, 0.f, 0.f};

    for (int kb = 0; kb < DIN; kb += 32) {
        __syncthreads();
        gload16(gAh + kb, dAh);  gload16(gAh + kb + 16 * DIN, dAh + 512);
        gload16(gAl + kb, dAl);  gload16(gAl + kb + 16 * DIN, dAl + 512);
        gload16(gBh + kb, dBh);  gload16(gBh + kb + 16 * DIN, dBh + 512);
        gload16(gBl + kb, dBl);  gload16(gBl + kb + 16 * DIN, dBl + 512);
        __syncthreads();

        bf16x8 Ah[4], Al[4], Bh[4], Bl[4];
#pragma unroll
        for (int fi = 0; fi < 4; ++fi) {
            Ah[fi] = *(const bf16x8*)(sAhi + offA[fi]);
            Al[fi] = *(const bf16x8*)(sAlo + offA[fi]);
            Bh[fi] = *(const bf16x8*)(sBhi + offB[fi]);
            Bl[fi] = *(const bf16x8*)(sBlo + offB[fi]);
        }
#pragma unroll
        for (int i = 0; i < 4; ++i)
#pragma unroll
            for (int j = 0; j < 4; ++j) {
                acc[i][j] = __builtin_amdgcn_mfma_f32_16x16x32_bf16(Ah[i], Bh[j], acc[i][j], 0, 0, 0);
                acc[i][j] = __builtin_amdgcn_mfma_f32_16x16x32_bf16(Ah[i], Bl[j], acc[i][j], 0, 0, 0);
                acc[i][j] = __builtin_amdgcn_mfma_f32_16x16x32_bf16(Al[i], Bh[j], acc[i][j], 0, 0, 0);
            }
    }

#pragma unroll
    for (int j = 0; j < 4; ++j) {
        const int e = bcol + wc * 64 + j * 16 + (lane & 15);
        const float bv = bias[e];
        const int ek = e & 1023;
        float* dst = ((e < DIN) ? Qb : Kb)
                   + ((size_t)(bf * NH + (ek >> 6)) * NSEQ) * HD + (ek & 63);
#pragma unroll
        for (int i = 0; i < 4; ++i) {
            const int rbase = n0 + wr * 64 + i * 16 + (lane >> 4) * 4;
            f32x4 v = acc[i][j];
#pragma unroll
            for (int rg = 0; rg < 4; ++rg)
                dst[(size_t)(rbase + rg) * HD] = v[rg] + bv;
        }
    }
}

// ---------------------------------------------------------------------------
// Kernel D: MFMA scores + fused softmax.
// Swapped operands: D[m][n] = sum_d K[m][d] Q[n][d]  (A=K rows, B=Q rows).
// C/D layout: lane holds q-row n = base+(lane&15); cols m = 16*mt+4*(lane>>4)+reg.
// Row n lives in lanes {n, n+16, n+32, n+48}: softmax = in-lane + shfl_xor(16,32).
// K chunk (128 rows f32) staged in LDS via gload16, XOR-swizzled both sides
// (rule 21: linear dest + inverse-swz source + swz read).
// grid = (8 row-tiles, 256 bfh), 256 threads (4 waves x 16 q-rows).
// ---------------------------------------------------------------------------
__global__ __launch_bounds__(256, 2)
void scores_mfma_kernel(const float* __restrict__ Qb, const float* __restrict__ Kb,
                        float* __restrict__ out)
{
    __shared__ float Kl_lds[128 * 64];   // 32 KB, one K chunk (f32)

    const int bfh = blockIdx.y;          // (b*8+f)*16+h
    const int rt  = blockIdx.x;
    const int t = threadIdx.x, w = t >> 6, lane = t & 63;
    const int g = lane >> 4, c16 = lane & 15;

    // ---- Q fragments (direct global; lane's q-row) ----
    const float* Qp = Qb + ((size_t)bfh * NSEQ + rt * 64 + 16 * w + c16) * HD;
    BF2 qf[2];
#pragma unroll
    for (int ks = 0; ks < 2; ++ks) {
        float4 a = *(const float4*)(Qp + 32 * ks + 8 * g);
        float4 b = *(const float4*)(Qp + 32 * ks + 8 * g + 4);
        qf[ks] = split8(a, b);
    }

    const float* Kp = Kb + (size_t)bfh * NSEQ * HD;
    const int swz = (lane & 7) << 4;     // read-side byte XOR (row&7 == lane&7)

    f32x4 acc[32];
#pragma unroll
    for (int i = 0; i < 32; ++i) acc[i] = (f32x4){0.f, 0.f, 0.f, 0.f};

#pragma unroll
    for (int c = 0; c < 4; ++c) {
        __syncthreads();                 // previous chunk fully consumed
#pragma unroll
        for (int i = 0; i < 8; ++i) {
            const int row = 32 * w + 4 * i + g;              // row in chunk
            const int slot = c16 ^ (row & 7);                // inverse-swz 16B slot
            gload16(Kp + ((size_t)(c * 128 + row)) * HD + slot * 4,
                    Kl_lds + (32 * w + 4 * i) * HD);
        }
        __syncthreads();                 // drains vmcnt: chunk ready

#pragma unroll
        for (int mtl = 0; mtl < 8; ++mtl) {
            const int row = 16 * mtl + c16;                  // K row in chunk
            const char* rbase = (const char*)Kl_lds + row * 256;
#pragma unroll
            for (int ks = 0; ks < 2; ++ks) {
                const int o = 128 * ks + 32 * g;
                float4 a = *(const float4*)(rbase + ((o)      ^ swz));
                float4 b = *(const float4*)(rbase + ((o + 16) ^ swz));
                BF2 kf = split8(a, b);
                f32x4 d = acc[c * 8 + mtl];
                d = __builtin_amdgcn_mfma_f32_16x16x32_bf16(kf.hi, qf[ks].hi, d, 0, 0, 0);
                d = __builtin_amdgcn_mfma_f32_16x16x32_bf16(kf.hi, qf[ks].lo, d, 0, 0, 0);
                d = __builtin_amdgcn_mfma_f32_16x16x32_bf16(kf.lo, qf[ks].hi, d, 0, 0, 0);
                acc[c * 8 + mtl] = d;
            }
        }
    }

    // ---- softmax over m (row n = rt*64 + 16w + c16) ----
    float m = -1e30f;
#pragma unroll
    for (int i = 0; i < 32; ++i)
#pragma unroll
        for (int r = 0; r < 4; ++r) m = fmaxf(m, acc[i][r]);
    m = fmaxf(m, __shfl_xor(m, 16));
    m = fmaxf(m, __shfl_xor(m, 32));

    float s = 0.f;
#pragma unroll
    for (int i = 0; i < 32; ++i)
#pragma unroll
        for (int r = 0; r < 4; ++r) {
            float e = __expf((acc[i][r] - m) * 0.125f);
            acc[i][r] = e;
            s += e;
        }
    s += __shfl_xor(s, 16);
    s += __shfl_xor(s, 32);
    const float inv = 1.f / s;

    // ---- store: 4 g-lanes of a row write one contiguous 64B line per i ----
    const int b = bfh >> 7, f = (bfh >> 4) & 7, h = bfh & 15;
    const int n = rt * 64 + 16 * w + c16;
    float* rowp = out + ((((size_t)(b * NH + h)) * NF + f) * NSEQ + n) * NSEQ;
#pragma unroll
    for (int i = 0; i < 32; ++i) {
        f32x4 v = acc[i] * inv;
        *(f32x4*)(rowp + 16 * i + 4 * g) = v;
    }
}

// ---------------------------------------------------------------------------
extern "C" void kernel_launch(void* const* d_in, const int* in_sizes, int n_in,
                              void* d_out, int out_size, void* d_ws, size_t ws_size,
                              hipStream_t stream)
{
    const float* x     = (const float*)d_in[0];
    const float* code  = (const float*)d_in[1];
    const float* w_c   = (const float*)d_in[2];
    const float* W     = (const float*)d_in[3];
    const float* bias  = (const float*)d_in[4];
    const float* gamma = (const float*)d_in[5];
    const float* beta  = (const float*)d_in[6];
    float* out = (float*)d_out;

    char* ws = (char*)d_ws;
    float* cond = (float*)(ws + WS_COND);
    short* Ahi  = (short*)(ws + WS_AHI);
    short* Alo  = (short*)(ws + WS_ALO);
    short* Bhi  = (short*)(ws + WS_BHI);
    short* Blo  = (short*)(ws + WS_BLO);
    float* Qb   = (float*)(ws + WS_QB);
    float* Kb   = (float*)(ws + WS_KB);

    cond_kernel<<<NF, 256, 0, stream>>>(w_c, code, gamma, beta, cond);
    split_x_kernel<<<4096, 256, 0, stream>>>(x, cond, Ahi, Alo);
    split_w_kernel<<<1024, 256, 0, stream>>>(W, Bhi, Blo);

    dim3 gP(16, 4, NB * NF);
    proj_mfma_kernel<<<gP, 256, 0, stream>>>(Ahi, Alo, Bhi, Blo, bias, Qb, Kb);

    dim3 gS(8, NB * NF * NH);
    scores_mfma_kernel<<<gS, 256, 0, stream>>>(Qb, Kb, out);
}